// Round 2
// baseline (368.241 us; speedup 1.0000x reference)
//
#include <hip/hip_runtime.h>
#include <hip/hip_fp16.h>

#define FP8_MAX 448.0f
#define M_ 32768
#define N_ 1024
#define K_ 1024
#define BM 128
#define BN 128
#define BK 64

typedef _Float16 f16x8 __attribute__((ext_vector_type(8)));
typedef _Float16 f16x4 __attribute__((ext_vector_type(4)));
typedef __fp16  h16x2 __attribute__((ext_vector_type(2)));   // cvt_pkrtz return type
typedef float f32x16 __attribute__((ext_vector_type(16)));

__device__ inline void gload_lds16(const void* g, void* l) {
    __builtin_amdgcn_global_load_lds(
        (const __attribute__((address_space(1))) void*)g,
        (__attribute__((address_space(3))) void*)l,
        16, 0, 0);
}

// ---------------- Kernel 1: weight quant + x partial amax (slot-based, no memset) ----
// blocks [0,1024): per-row weight quant. blocks [1024,3072): x amax partials.
__global__ __launch_bounds__(256) void prep_kernel(const float* __restrict__ x,
                                                   const float* __restrict__ w,
                                                   float* __restrict__ xamax_part,
                                                   float* __restrict__ wscale,
                                                   _Float16* __restrict__ wq,
                                                   int n) {
    __shared__ float sm[4];
    if (blockIdx.x < 1024) {
        int row = blockIdx.x;
        const float4* wr4 = (const float4*)(w + (size_t)row * K_);
        float4 v = wr4[threadIdx.x];  // 256 threads x 4 = 1024
        float m = fmaxf(fmaxf(fabsf(v.x), fabsf(v.y)), fmaxf(fabsf(v.z), fabsf(v.w)));
        #pragma unroll
        for (int off = 32; off > 0; off >>= 1)
            m = fmaxf(m, __shfl_down(m, off, 64));
        if ((threadIdx.x & 63) == 0) sm[threadIdx.x >> 6] = m;
        __syncthreads();
        m = fmaxf(fmaxf(sm[0], sm[1]), fmaxf(sm[2], sm[3]));
        float scale = fmaxf(m / FP8_MAX, 1e-12f);
        if (threadIdx.x == 0) wscale[row] = scale;
        float inv = 1.0f / scale;
        f16x4 o;
        o[0] = (_Float16)rintf(fminf(fmaxf(v.x * inv, -FP8_MAX), FP8_MAX));
        o[1] = (_Float16)rintf(fminf(fmaxf(v.y * inv, -FP8_MAX), FP8_MAX));
        o[2] = (_Float16)rintf(fminf(fmaxf(v.z * inv, -FP8_MAX), FP8_MAX));
        o[3] = (_Float16)rintf(fminf(fmaxf(v.w * inv, -FP8_MAX), FP8_MAX));
        ((f16x4*)(wq + (size_t)row * K_))[threadIdx.x] = o;
    } else {
        float m = 0.0f;
        const float4* x4 = (const float4*)x;
        int n4 = n >> 2;
        int stride = 2048 * 256;
        for (int i = (blockIdx.x - 1024) * 256 + threadIdx.x; i < n4; i += stride) {
            float4 v = x4[i];
            m = fmaxf(m, fmaxf(fmaxf(fabsf(v.x), fabsf(v.y)),
                               fmaxf(fabsf(v.z), fabsf(v.w))));
        }
        #pragma unroll
        for (int off = 32; off > 0; off >>= 1)
            m = fmaxf(m, __shfl_down(m, off, 64));
        if ((threadIdx.x & 63) == 0) sm[threadIdx.x >> 6] = m;
        __syncthreads();
        if (threadIdx.x == 0) {
            xamax_part[blockIdx.x - 1024] =
                fmaxf(fmaxf(sm[0], sm[1]), fmaxf(sm[2], sm[3]));
        }
    }
}

// ---------------- Kernel 2: FUSED x-quant + fp16 MFMA GEMM (32x32x16) + dequant ----
// Each block: reduce 2048 amax partials (L2-hot, deterministic, identical order in
// every block -> bit-identical iscale), then per K-tile load A as fp32, quantize
// q = rint(x*inv) in registers (clamp provably no-op: scale = max(amax/448,1e-12)
// guarantees |x|*inv <= 448), pack via v_cvt_pkrtz (integers -> exact in fp16
// regardless of rounding mode), and ds_write_b128 into the XOR-swizzled LDS layout
// (chunk c of row r at slot c^(r&7)) — identical layout to the previous gload_lds
// source-side swizzle, so the MFMA readback is unchanged. B (wq, 2 MB,
// L3-resident) keeps global_load_lds.
__global__ __launch_bounds__(256) void gemm_kernel(const float* __restrict__ x,
                                                   const _Float16* __restrict__ wq,
                                                   const float* __restrict__ xamax_part,
                                                   const float* __restrict__ wscale,
                                                   const float* __restrict__ bias,
                                                   float* __restrict__ out) {
    __shared__ __align__(16) _Float16 sA[BM * BK];
    __shared__ __align__(16) _Float16 sB[BN * BK];

    const int tid = threadIdx.x;

    // ---- per-block reduce of x-amax partials -> iscale (reuse sA as scratch) ----
    const float4* p4 = (const float4*)xamax_part;  // 512 float4
    float4 pa = p4[tid];
    float4 pb = p4[tid + 256];
    float m = fmaxf(fmaxf(fmaxf(pa.x, pa.y), fmaxf(pa.z, pa.w)),
                    fmaxf(fmaxf(pb.x, pb.y), fmaxf(pb.z, pb.w)));
    #pragma unroll
    for (int off = 32; off > 0; off >>= 1)
        m = fmaxf(m, __shfl_down(m, off, 64));
    float* red = (float*)sA;
    if ((tid & 63) == 0) red[tid >> 6] = m;
    __syncthreads();
    const float amax = fmaxf(fmaxf(red[0], red[1]), fmaxf(red[2], red[3]));
    __syncthreads();  // protect scratch before first A-tile ds_write
    const float iscale = fmaxf(amax / FP8_MAX, 1e-12f);
    const float inv = 1.0f / iscale;

    const int wave = tid >> 6;
    const int lane = tid & 63;
    const int h   = lane >> 5;    // half-wave
    const int m32 = lane & 31;
    const int m7  = m32 & 7;
    const int wm = (wave >> 1) * 64;
    const int wn = (wave & 1) * 64;

    // A-sharing blocks differ by multiples of 256 (≡0 mod 8) → same XCD → L2 reuse.
    const int m0 = (int)(blockIdx.x & 255) * BM;
    const int n0 = (int)(blockIdx.x >> 8) * BN;

    // B staging via global_load_lds: thread t loads 16B, source-side swizzle.
    const int trow = tid >> 3;                               // 0..31
    const int tcol = (((tid & 7) ^ (trow & 7)) * 8);         // swizzled source chunk
    const _Float16* Bg = wq + ((size_t)(n0 + trow)) * K_ + tcol;
    char* lB = (char*)sB + wave * 1024;  // wave-uniform base; HW adds lane*16

    // A staging (reg): row = tid>>3 (+32/round), logical chunk = tid&7,
    // write at physical chunk (c ^ (row&7)); row&7 invariant across rounds.
    const int arow = tid >> 3;
    const int ach  = tid & 7;
    const float* Ag = x + (size_t)(m0 + arow) * K_ + ach * 8;
    _Float16* Aw = sA + (size_t)arow * BK + ((ach ^ (arow & 7)) * 8);

    f32x16 acc[2][2] = {};

    for (int kt = 0; kt < K_; kt += BK) {
        #pragma unroll
        for (int rr = 0; rr < 4; ++rr)
            gload_lds16(Bg + kt + (size_t)(rr * 32) * K_, lB + rr * 4096);
        #pragma unroll
        for (int rr = 0; rr < 4; ++rr) {
            const float* src = Ag + kt + (size_t)(rr * 32) * K_;
            float4 v0 = *(const float4*)src;
            float4 v1 = *(const float4*)(src + 4);
            h16x2 t0 = __builtin_amdgcn_cvt_pkrtz(rintf(v0.x * inv), rintf(v0.y * inv));
            h16x2 t1 = __builtin_amdgcn_cvt_pkrtz(rintf(v0.z * inv), rintf(v0.w * inv));
            h16x2 t2 = __builtin_amdgcn_cvt_pkrtz(rintf(v1.x * inv), rintf(v1.y * inv));
            h16x2 t3 = __builtin_amdgcn_cvt_pkrtz(rintf(v1.z * inv), rintf(v1.w * inv));
            f16x8 q;
            q[0] = (_Float16)t0[0]; q[1] = (_Float16)t0[1];
            q[2] = (_Float16)t1[0]; q[3] = (_Float16)t1[1];
            q[4] = (_Float16)t2[0]; q[5] = (_Float16)t2[1];
            q[6] = (_Float16)t3[0]; q[7] = (_Float16)t3[1];
            *(f16x8*)(Aw + (size_t)(rr * 32) * BK) = q;
        }
        __syncthreads();
        #pragma unroll
        for (int ks = 0; ks < 4; ++ks) {       // K chunks of 16 within the tile
            f16x8 a[2], b[2];
            const int chunk = ks * 2 + h;      // logical 16B-chunk (8 halves)
            const int pos = (chunk ^ m7) * 8;  // swizzled physical offset (halves)
            #pragma unroll
            for (int i = 0; i < 2; ++i)
                a[i] = *(const f16x8*)&sA[(wm + i * 32 + m32) * BK + pos];
            #pragma unroll
            for (int j = 0; j < 2; ++j)
                b[j] = *(const f16x8*)&sB[(wn + j * 32 + m32) * BK + pos];
            #pragma unroll
            for (int i = 0; i < 2; ++i)
                #pragma unroll
                for (int j = 0; j < 2; ++j)
                    acc[i][j] = __builtin_amdgcn_mfma_f32_32x32x16_f16(a[i], b[j], acc[i][j], 0, 0, 0);
        }
        __syncthreads();
    }

    #pragma unroll
    for (int j = 0; j < 2; ++j) {
        int col = n0 + wn + j * 32 + m32;
        float sc = iscale * wscale[col];
        float bs = bias[col];
        #pragma unroll
        for (int i = 0; i < 2; ++i) {
            int rb = m0 + wm + i * 32 + 4 * h;
            #pragma unroll
            for (int reg = 0; reg < 16; ++reg) {
                int row = rb + (reg & 3) + 8 * (reg >> 2);
                out[(size_t)row * N_ + col] = acc[i][j][reg] * sc + bs;
            }
        }
    }
}

extern "C" void kernel_launch(void* const* d_in, const int* in_sizes, int n_in,
                              void* d_out, int out_size, void* d_ws, size_t ws_size,
                              hipStream_t stream) {
    const float* x    = (const float*)d_in[0];
    const float* w    = (const float*)d_in[1];
    const float* bias = (const float*)d_in[2];
    float* out = (float*)d_out;

    char* ws = (char*)d_ws;
    float* xamax_part  = (float*)(ws + 1024);                  // 8 KB (2048 slots)
    float* wscale      = (float*)(ws + 16384);                 // 4 KB
    _Float16* wq       = (_Float16*)(ws + 32768);              // 2 MB

    prep_kernel<<<3072, 256, 0, stream>>>(x, w, xamax_part, wscale, wq, M_ * K_);
    gemm_kernel<<<2048, 256, 0, stream>>>(x, wq, xamax_part, wscale, bias, out);
}

// Round 3
// 316.918 us; speedup vs baseline: 1.1619x; 1.1619x over previous
//
#include <hip/hip_runtime.h>
#include <hip/hip_fp16.h>

#define FP8_MAX 448.0f
#define M_ 32768
#define N_ 1024
#define K_ 1024
#define BM 128
#define BN 128
#define BK 64

typedef _Float16 f16x8 __attribute__((ext_vector_type(8)));
typedef _Float16 f16x4 __attribute__((ext_vector_type(4)));
typedef __fp16  h16x2 __attribute__((ext_vector_type(2)));   // cvt_pkrtz return type
typedef float f32x16 __attribute__((ext_vector_type(16)));

__device__ inline void gload_lds16(const void* g, void* l) {
    __builtin_amdgcn_global_load_lds(
        (const __attribute__((address_space(1))) void*)g,
        (__attribute__((address_space(3))) void*)l,
        16, 0, 0);
}

// quantize 8 fp32 -> 8 fp16 integers (clamp provably no-op: |x|*inv <= 448)
__device__ inline f16x8 quant8(float4 v0, float4 v1, float inv) {
    h16x2 t0 = __builtin_amdgcn_cvt_pkrtz(rintf(v0.x * inv), rintf(v0.y * inv));
    h16x2 t1 = __builtin_amdgcn_cvt_pkrtz(rintf(v0.z * inv), rintf(v0.w * inv));
    h16x2 t2 = __builtin_amdgcn_cvt_pkrtz(rintf(v1.x * inv), rintf(v1.y * inv));
    h16x2 t3 = __builtin_amdgcn_cvt_pkrtz(rintf(v1.z * inv), rintf(v1.w * inv));
    f16x8 q;
    q[0] = (_Float16)t0[0]; q[1] = (_Float16)t0[1];
    q[2] = (_Float16)t1[0]; q[3] = (_Float16)t1[1];
    q[4] = (_Float16)t2[0]; q[5] = (_Float16)t2[1];
    q[6] = (_Float16)t3[0]; q[7] = (_Float16)t3[1];
    return q;
}

// ---------------- Kernel 1: weight quant + x partial amax (unchanged) ----------------
__global__ __launch_bounds__(256) void prep_kernel(const float* __restrict__ x,
                                                   const float* __restrict__ w,
                                                   float* __restrict__ xamax_part,
                                                   float* __restrict__ wscale,
                                                   _Float16* __restrict__ wq,
                                                   int n) {
    __shared__ float sm[4];
    if (blockIdx.x < 1024) {
        int row = blockIdx.x;
        const float4* wr4 = (const float4*)(w + (size_t)row * K_);
        float4 v = wr4[threadIdx.x];  // 256 threads x 4 = 1024
        float m = fmaxf(fmaxf(fabsf(v.x), fabsf(v.y)), fmaxf(fabsf(v.z), fabsf(v.w)));
        #pragma unroll
        for (int off = 32; off > 0; off >>= 1)
            m = fmaxf(m, __shfl_down(m, off, 64));
        if ((threadIdx.x & 63) == 0) sm[threadIdx.x >> 6] = m;
        __syncthreads();
        m = fmaxf(fmaxf(sm[0], sm[1]), fmaxf(sm[2], sm[3]));
        float scale = fmaxf(m / FP8_MAX, 1e-12f);
        if (threadIdx.x == 0) wscale[row] = scale;
        float inv = 1.0f / scale;
        f16x4 o;
        o[0] = (_Float16)rintf(fminf(fmaxf(v.x * inv, -FP8_MAX), FP8_MAX));
        o[1] = (_Float16)rintf(fminf(fmaxf(v.y * inv, -FP8_MAX), FP8_MAX));
        o[2] = (_Float16)rintf(fminf(fmaxf(v.z * inv, -FP8_MAX), FP8_MAX));
        o[3] = (_Float16)rintf(fminf(fmaxf(v.w * inv, -FP8_MAX), FP8_MAX));
        ((f16x4*)(wq + (size_t)row * K_))[threadIdx.x] = o;
    } else {
        float m = 0.0f;
        const float4* x4 = (const float4*)x;
        int n4 = n >> 2;
        int stride = 2048 * 256;
        for (int i = (blockIdx.x - 1024) * 256 + threadIdx.x; i < n4; i += stride) {
            float4 v = x4[i];
            m = fmaxf(m, fmaxf(fmaxf(fabsf(v.x), fabsf(v.y)),
                               fmaxf(fabsf(v.z), fabsf(v.w))));
        }
        #pragma unroll
        for (int off = 32; off > 0; off >>= 1)
            m = fmaxf(m, __shfl_down(m, off, 64));
        if ((threadIdx.x & 63) == 0) sm[threadIdx.x >> 6] = m;
        __syncthreads();
        if (threadIdx.x == 0) {
            xamax_part[blockIdx.x - 1024] =
                fmaxf(fmaxf(sm[0], sm[1]), fmaxf(sm[2], sm[3]));
        }
    }
}

// ---------------- Kernel 2: FUSED x-quant + fp16 MFMA GEMM, pipelined ---------------
// v2 changes vs v1:
//  * n-fast per-XCD block swizzle: the 8 blocks sharing an A-panel are consecutive
//    on one XCD -> co-resident -> A fetched once into that XCD's L2 (was 2.6x).
//  * A staged via reg-prefetch one K-tile ahead (T14): loads for kt+1 issued before
//    the MFMA phase of kt (in flight alongside B's global_load_lds, so the barrier
//    drain is free); quant+ds_write into double-buffered sA happens after the
//    post-MFMA barrier when the registers are already resident. A-load latency is
//    off the critical path.
__global__ __launch_bounds__(256) void gemm_kernel(const float* __restrict__ x,
                                                   const _Float16* __restrict__ wq,
                                                   const float* __restrict__ xamax_part,
                                                   const float* __restrict__ wscale,
                                                   const float* __restrict__ bias,
                                                   float* __restrict__ out) {
    __shared__ __align__(16) _Float16 sA[2][BM * BK];   // double-buffered (32 KB)
    __shared__ __align__(16) _Float16 sB[BN * BK];      // single-buffered (16 KB)

    const int tid = threadIdx.x;

    // ---- per-block reduce of x-amax partials -> iscale (sA as scratch) ----
    const float4* p4 = (const float4*)xamax_part;  // 512 float4
    float4 pa = p4[tid];
    float4 pb = p4[tid + 256];
    float m = fmaxf(fmaxf(fmaxf(pa.x, pa.y), fmaxf(pa.z, pa.w)),
                    fmaxf(fmaxf(pb.x, pb.y), fmaxf(pb.z, pb.w)));
    #pragma unroll
    for (int off = 32; off > 0; off >>= 1)
        m = fmaxf(m, __shfl_down(m, off, 64));
    float* red = (float*)sA;
    if ((tid & 63) == 0) red[tid >> 6] = m;
    __syncthreads();
    const float amax = fmaxf(fmaxf(red[0], red[1]), fmaxf(red[2], red[3]));
    __syncthreads();  // protect scratch before first A-tile ds_write
    const float iscale = fmaxf(amax / FP8_MAX, 1e-12f);
    const float inv = 1.0f / iscale;

    const int wave = tid >> 6;
    const int lane = tid & 63;
    const int h   = lane >> 5;    // half-wave
    const int m32 = lane & 31;
    const int m7  = m32 & 7;
    const int wm = (wave >> 1) * 64;
    const int wn = (wave & 1) * 64;

    // n-fast per-XCD swizzle: xcd = b&7; per-XCD seq s = b>>3;
    // n-index = s&7 (fast), m-index = (s>>3)*8 + xcd.
    const int bb = (int)blockIdx.x;
    const int n0 = (((bb >> 3) & 7)) * BN;
    const int m0 = (((bb >> 6) << 3) + (bb & 7)) * BM;

    // B staging via global_load_lds: thread t loads 16B, source-side swizzle.
    const int trow = tid >> 3;                               // 0..31
    const int tcol = (((tid & 7) ^ (trow & 7)) * 8);         // swizzled source chunk
    const _Float16* Bg = wq + ((size_t)(n0 + trow)) * K_ + tcol;
    char* lB = (char*)sB + wave * 1024;  // wave-uniform base; HW adds lane*16

    // A staging (reg): row = tid>>3 (+32/round), logical chunk = tid&7,
    // write at physical chunk (c ^ (row&7)); row&7 invariant across rounds.
    const int arow = tid >> 3;
    const int ach  = tid & 7;
    const float* Ag = x + (size_t)(m0 + arow) * K_ + ach * 8;
    _Float16* Aw0 = (_Float16*)sA + (size_t)arow * BK + ((ach ^ (arow & 7)) * 8);

    f32x16 acc[2][2] = {};
    float4 pv[4][2];

    // ---- prologue: stage tile kt=0 into sA[0] ----
    #pragma unroll
    for (int rr = 0; rr < 4; ++rr) {
        const float* src = Ag + (size_t)(rr * 32) * K_;
        pv[rr][0] = *(const float4*)src;
        pv[rr][1] = *(const float4*)(src + 4);
    }
    #pragma unroll
    for (int rr = 0; rr < 4; ++rr)
        *(f16x8*)(Aw0 + (size_t)(rr * 32) * BK) = quant8(pv[rr][0], pv[rr][1], inv);

    int buf = 0;
    for (int kt = 0; kt < K_; kt += BK) {
        // B tile kt (async -> LDS)
        #pragma unroll
        for (int rr = 0; rr < 4; ++rr)
            gload_lds16(Bg + kt + (size_t)(rr * 32) * K_, lB + rr * 4096);
        // issue A loads for tile kt+1 (wrap on last iter; data unused then)
        const int kn = (kt + BK) & (K_ - 1);
        #pragma unroll
        for (int rr = 0; rr < 4; ++rr) {
            const float* src = Ag + kn + (size_t)(rr * 32) * K_;
            pv[rr][0] = *(const float4*)src;
            pv[rr][1] = *(const float4*)(src + 4);
        }
        __syncthreads();  // sB(kt) + sA[buf](kt) visible; prefetch drained too (free)

        const _Float16* sAb = (const _Float16*)sA + (size_t)buf * (BM * BK);
        #pragma unroll
        for (int ks = 0; ks < 4; ++ks) {       // K chunks of 16 within the tile
            f16x8 a[2], b[2];
            const int chunk = ks * 2 + h;      // logical 16B-chunk (8 halves)
            const int pos = (chunk ^ m7) * 8;  // swizzled physical offset (halves)
            #pragma unroll
            for (int i = 0; i < 2; ++i)
                a[i] = *(const f16x8*)&sAb[(wm + i * 32 + m32) * BK + pos];
            #pragma unroll
            for (int j = 0; j < 2; ++j)
                b[j] = *(const f16x8*)&sB[(wn + j * 32 + m32) * BK + pos];
            #pragma unroll
            for (int i = 0; i < 2; ++i)
                #pragma unroll
                for (int j = 0; j < 2; ++j)
                    acc[i][j] = __builtin_amdgcn_mfma_f32_32x32x16_f16(a[i], b[j], acc[i][j], 0, 0, 0);
        }
        __syncthreads();  // all waves done reading sA[buf], sB

        if (kt + BK < K_) {
            // quant tile kt+1 (regs already resident) into the other buffer
            _Float16* Awn = Aw0 + (size_t)(buf ^ 1) * (BM * BK);
            #pragma unroll
            for (int rr = 0; rr < 4; ++rr)
                *(f16x8*)(Awn + (size_t)(rr * 32) * BK) = quant8(pv[rr][0], pv[rr][1], inv);
            buf ^= 1;
        }
    }

    #pragma unroll
    for (int j = 0; j < 2; ++j) {
        int col = n0 + wn + j * 32 + m32;
        float sc = iscale * wscale[col];
        float bs = bias[col];
        #pragma unroll
        for (int i = 0; i < 2; ++i) {
            int rb = m0 + wm + i * 32 + 4 * h;
            #pragma unroll
            for (int reg = 0; reg < 16; ++reg) {
                int row = rb + (reg & 3) + 8 * (reg >> 2);
                out[(size_t)row * N_ + col] = acc[i][j][reg] * sc + bs;
            }
        }
    }
}

extern "C" void kernel_launch(void* const* d_in, const int* in_sizes, int n_in,
                              void* d_out, int out_size, void* d_ws, size_t ws_size,
                              hipStream_t stream) {
    const float* x    = (const float*)d_in[0];
    const float* w    = (const float*)d_in[1];
    const float* bias = (const float*)d_in[2];
    float* out = (float*)d_out;

    char* ws = (char*)d_ws;
    float* xamax_part  = (float*)(ws + 1024);                  // 8 KB (2048 slots)
    float* wscale      = (float*)(ws + 16384);                 // 4 KB
    _Float16* wq       = (_Float16*)(ws + 32768);              // 2 MB

    prep_kernel<<<3072, 256, 0, stream>>>(x, w, xamax_part, wscale, wq, M_ * K_);
    gemm_kernel<<<2048, 256, 0, stream>>>(x, wq, xamax_part, wscale, bias, out);
}